// Round 15
// baseline (148.681 us; speedup 1.0000x reference)
//
#include <hip/hip_runtime.h>
#include <hip/hip_bf16.h>
#include <math.h>

#define HD 128          // N_HEADS * OUT_FEATS
#define IN_F 256
#define NEG_SLOPE 0.2f
#define NMAX 50000      // problem-fixed node count (LDS histogram capacity)
#define GGRID 256       // persistent gemm grid (1 block/CU, 8 waves)
#define CSRC 32         // src-histogram chunk count (only totals needed)

typedef __attribute__((ext_vector_type(8))) short short8;
typedef __attribute__((ext_vector_type(4))) float f32x4;

__device__ __forceinline__ unsigned short f2bf(float x) {
    __hip_bfloat16 b = __float2bfloat16(x);
    return *(unsigned short*)&b;
}
__device__ __forceinline__ float bf2f(unsigned short u) {
    unsigned int v = ((unsigned int)u) << 16;
    float f;
    __builtin_memcpy(&f, &v, 4);
    return f;
}
__device__ __forceinline__ short8 pack8(float4 f0, float4 f1) {
    short8 v;
    v[0] = (short)f2bf(f0.x); v[1] = (short)f2bf(f0.y);
    v[2] = (short)f2bf(f0.z); v[3] = (short)f2bf(f0.w);
    v[4] = (short)f2bf(f1.x); v[5] = (short)f2bf(f1.y);
    v[6] = (short)f2bf(f1.z); v[7] = (short)f2bf(f1.w);
    return v;
}

// ---------------- weights f32->bf16 + ew columns, fused ----------------
// blocks 0..3: ew rows for head b; blocks 4..: w16 conversion.
__global__ __launch_bounds__(256) void cvt_ew_kernel(
    const float4* __restrict__ wfc4, const float4* __restrict__ wres4,
    const float* __restrict__ wfc, const float* __restrict__ attn_l,
    const float* __restrict__ attn_r, ushort4* __restrict__ w16,
    unsigned short* __restrict__ ew16, int n4each) {
    int b = blockIdx.x;
    if (b < 4) {
        int h = b, k = threadIdx.x;
        float sl = 0.f, sr = 0.f;
#pragma unroll 8
        for (int d = 0; d < 32; d++) {
            float w = wfc[(size_t)(h * 32 + d) * IN_F + k];
            sl += attn_l[h * 32 + d] * w;
            sr += attn_r[h * 32 + d] * w;
        }
        ew16[h * IN_F + k] = f2bf(sl);
        ew16[(4 + h) * IN_F + k] = f2bf(sr);
        ew16[(8 + h) * IN_F + k] = 0;
        ew16[(12 + h) * IN_F + k] = 0;
        return;
    }
    int idx = (b - 4) * 256 + threadIdx.x;
    if (idx >= 2 * n4each) return;
    float4 f = (idx < n4each) ? wfc4[idx] : wres4[idx - n4each];
    ushort4 u;
    u.x = f2bf(f.x); u.y = f2bf(f.y); u.z = f2bf(f.z); u.w = f2bf(f.w);
    w16[idx] = u;
}

// ---------------- per-chunk LDS histogram (uint16-packed, no global atomics) ----
// blocks 0..C-1: dst chunks (size chunk); blocks C..C+CSRC-1: src chunks (chunk_s).
__global__ __launch_bounds__(512) void hist_kernel(const int* __restrict__ src,
                                                   const int* __restrict__ dst,
                                                   unsigned short* __restrict__ pc_src,
                                                   unsigned short* __restrict__ pc_dst,
                                                   int N, int E, int C, int chunk,
                                                   int chunk_s) {
    __shared__ unsigned int h[NMAX / 2];   // 100 KB packed uint16 counts
    int tid = threadIdx.x;
    int nh = N >> 1;                        // N even
    uint4* h4 = (uint4*)h;
    for (int i = tid; i < (nh >> 2); i += 512) h4[i] = make_uint4(0, 0, 0, 0);
    for (int i = (nh & ~3) + tid; i < nh; i += 512) h[i] = 0;
    __syncthreads();

    int b = blockIdx.x;
    bool isSrc = (b >= C);
    const int* arr = isSrc ? src : dst;
    int c = isSrc ? (b - C) : b;
    int ch = isSrc ? chunk_s : chunk;
    int e0 = c * ch, e1 = min(E, (c + 1) * ch);
    for (int e = e0 + tid; e < e1; e += 512) {
        int v = arr[e];
        atomicAdd(&h[v >> 1], 1u << ((v & 1) << 4));
    }
    __syncthreads();

    unsigned short* pc = (isSrc ? pc_src : pc_dst) + (size_t)c * N;
    uint4* pc4 = (uint4*)pc;
    for (int i = tid; i < (nh >> 2); i += 512) pc4[i] = h4[i];
    for (int i = (nh & ~3) + tid; i < nh; i += 512) ((unsigned int*)pc)[i] = h[i];
}

// ---------------- per-node chunk prefix (in place) + degrees + scan1 ----------------
__global__ __launch_bounds__(256) void sum_scan1_kernel(
    const unsigned short* __restrict__ pc_src, unsigned short* __restrict__ pc_dst,
    int* __restrict__ out_cnt, int* __restrict__ deg, int* __restrict__ bsum,
    int N, int C) {
    __shared__ int wsum[4];
    int n = blockIdx.x * 256 + threadIdx.x;
    int sd = 0;
    if (n < N) {
        int ss = 0;
#pragma unroll 4
        for (int c = 0; c < CSRC; c++) ss += pc_src[(size_t)c * N + n];
        for (int c = 0; c < C; c++) {
            unsigned short v = pc_dst[(size_t)c * N + n];
            pc_dst[(size_t)c * N + n] = (unsigned short)sd;  // exclusive chunk prefix
            sd += v;
        }
        out_cnt[n] = ss;
        deg[n] = sd;
    }
    int v = (n < N) ? sd : 0;
#pragma unroll
    for (int d = 1; d < 64; d <<= 1) v += __shfl_xor(v, d);
    if ((threadIdx.x & 63) == 0) wsum[threadIdx.x >> 6] = v;
    __syncthreads();
    if (threadIdx.x == 0) bsum[blockIdx.x] = wsum[0] + wsum[1] + wsum[2] + wsum[3];
}

// ---------------- scan3 with internal block-sum scan (absorbs old scan2) ----------
__global__ __launch_bounds__(256) void scan3_kernel(const int* __restrict__ deg,
                                                    const int* __restrict__ bsum,
                                                    int* __restrict__ row_start,
                                                    int N, int nb, int E) {
    __shared__ int wsum[4];
    __shared__ int sbo[256];
    int tid = threadIdx.x, lane = tid & 63, wid = tid >> 6;
    // --- internal scan of bsum (nb <= 256) ---
    {
        int v = (tid < nb) ? bsum[tid] : 0;
        int incl = v;
#pragma unroll
        for (int d = 1; d < 64; d <<= 1) {
            int t = __shfl_up(incl, d);
            if (lane >= d) incl += t;
        }
        if (lane == 63) wsum[wid] = incl;
        __syncthreads();
        int woff = 0;
        for (int w = 0; w < wid; w++) woff += wsum[w];
        sbo[tid] = woff + incl - v;    // exclusive prefix of block sums
        __syncthreads();
    }
    int boff = sbo[blockIdx.x];
    if (blockIdx.x == 0 && tid == 0) row_start[N] = E;
    __syncthreads();

    int i = blockIdx.x * 256 + tid;
    int v = (i < N) ? deg[i] : 0;
    int incl = v;
#pragma unroll
    for (int d = 1; d < 64; d <<= 1) {
        int t = __shfl_up(incl, d);
        if (lane >= d) incl += t;
    }
    if (lane == 63) wsum[wid] = incl;
    __syncthreads();
    int woff = 0;
    for (int w = 0; w < wid; w++) woff += wsum[w];
    int excl = boff + woff + incl - v;
    if (i < N) row_start[i] = excl;
}

// ---------------- placement: LDS cursors seeded from chunk prefix ----------------
__global__ __launch_bounds__(512) void place_kernel(const int* __restrict__ src,
                                                    const int* __restrict__ dst,
                                                    const unsigned short* __restrict__ chunkpre,
                                                    const int* __restrict__ row_start,
                                                    int* __restrict__ esrc,
                                                    int N, int E, int chunk) {
    __shared__ unsigned int cur[NMAX / 2];   // packed uint16 cursors
    int tid = threadIdx.x;
    int nh = N >> 1;
    const unsigned short* cp = chunkpre + (size_t)blockIdx.x * N;
    const uint4* cp4 = (const uint4*)cp;
    uint4* cur4 = (uint4*)cur;
    for (int i = tid; i < (nh >> 2); i += 512) cur4[i] = cp4[i];
    for (int i = (nh & ~3) + tid; i < nh; i += 512) cur[i] = ((const unsigned int*)cp)[i];
    __syncthreads();

    int e1 = min(E, (int)(blockIdx.x + 1) * chunk);
    for (int e = blockIdx.x * chunk + tid; e < e1; e += 512) {
        int d = dst[e], s = src[e];
        int sh = (d & 1) << 4;
        unsigned int old = atomicAdd(&cur[d >> 1], 1u << sh);
        int rank = (old >> sh) & 0xffff;
        esrc[row_start[d] + rank] = s;
    }
}

// ---------------- persistent fused GEMM: B panel in LDS, no spill ----------------
// 256 blocks x 8 waves (512 thr). sB = full 256x256 bf16 weight panel (128 KiB,
// staged once, XOR-swizzled). Per 32-row tile: reg-prefetch f32 A -> cvt -> sA
// (16 KiB) -> pure ds_read+MFMA k-loop. Wave w owns cols w*32..+31; waves 0-3
// write h16 (+norm), 4-7 write resid16; wave 0 also computes el/er via ew16.
__global__ __launch_bounds__(512, 1) void gemm_fused(
    const float* __restrict__ feat, const __hip_bfloat16* __restrict__ w16,
    const __hip_bfloat16* __restrict__ ew16, const int* __restrict__ out_cnt,
    unsigned short* __restrict__ h16, unsigned short* __restrict__ resid16,
    float* __restrict__ el, float* __restrict__ er, int N, int ntiles) {
    __shared__ unsigned short sB[256 * 256];  // 128 KiB
    __shared__ unsigned short sA[32 * 256];   // 16 KiB
    int tid = threadIdx.x;
    int lane = tid & 63, w = tid >> 6;
    int l15 = lane & 15, lg = lane >> 4;
    int c0 = w * 32;
    bool w0 = (w == 0);
    bool isH = (w < 4);
    int colloc = c0 & 127;

    // ---- stage B once: 8192 granules (16 per thread), XOR-swizzled by col ----
#pragma unroll
    for (int it = 0; it < 16; ++it) {
        int idx = it * 512 + tid;
        int c = idx >> 5, g = idx & 31;
        short8 v = *(const short8*)(w16 + (size_t)c * IN_F + g * 8);
        *(short8*)&sB[c * 256 + ((g ^ (c & 7)) * 8)] = v;
    }
    // ew fragment for wave 0 (8 short8 regs)
    short8 ereg[8];
    if (w0) {
        const __hip_bfloat16* ep = ew16 + (size_t)l15 * IN_F + lg * 8;
#pragma unroll
        for (int kk = 0; kk < 8; kk++) ereg[kk] = *(const short8*)(ep + kk * 32);
    }

    // A-stage mapping: granule idx = i*512+tid -> row idx>>5, 8-col group idx&31
    int srow[2], sgc[2];
#pragma unroll
    for (int i = 0; i < 2; i++) {
        int idx = i * 512 + tid;
        srow[i] = idx >> 5;
        sgc[i] = idx & 31;
    }

    float4 fA[2][2];
    int t = blockIdx.x;
    // prologue: load tile t into regs
#pragma unroll
    for (int i = 0; i < 2; i++) {
        int gm = t * 32 + srow[i];
        gm = (gm < N) ? gm : (N - 1);
        const float4* fp = (const float4*)(feat + (size_t)gm * IN_F + sgc[i] * 8);
        fA[i][0] = fp[0];
        fA[i][1] = fp[1];
    }

    for (; t < ntiles; t += GGRID) {
        __syncthreads();   // all waves done reading sA (and, first iter, sB staged)
        // ---- convert prefetched regs -> sA (fA holds tile t) ----
#pragma unroll
        for (int i = 0; i < 2; i++)
            *(short8*)&sA[srow[i] * 256 + ((sgc[i] ^ (srow[i] & 7)) * 8)] =
                pack8(fA[i][0], fA[i][1]);
        __syncthreads();   // sA staged

        // ---- issue next tile's loads (latency hides under k-loop + epilogue) ----
        int tn = t + GGRID;
        if (tn < ntiles) {
#pragma unroll
            for (int i = 0; i < 2; i++) {
                int gm = tn * 32 + srow[i];
                gm = (gm < N) ? gm : (N - 1);
                const float4* fp = (const float4*)(feat + (size_t)gm * IN_F + sgc[i] * 8);
                fA[i][0] = fp[0];
                fA[i][1] = fp[1];
            }
        }

        // ---- k-loop: pure LDS reads + MFMA ----
        f32x4 acc[2][2], accE[2];
#pragma unroll
        for (int i = 0; i < 2; i++) {
            accE[i] = (f32x4){0.f, 0.f, 0.f, 0.f};
#pragma unroll
            for (int j = 0; j < 2; j++) acc[i][j] = (f32x4){0.f, 0.f, 0.f, 0.f};
        }
#pragma unroll
        for (int kk = 0; kk < 8; kk++) {
            short8 a[2], b[2];
#pragma unroll
            for (int mi = 0; mi < 2; mi++) {
                int row = mi * 16 + l15;
                int gs = (kk * 4 + lg) ^ (row & 7);
                a[mi] = *(const short8*)&sA[row * 256 + gs * 8];
            }
#pragma unroll
            for (int ni = 0; ni < 2; ni++) {
                int c = c0 + ni * 16 + l15;
                int gsb = (kk * 4 + lg) ^ (c & 7);
                b[ni] = *(const short8*)&sB[c * 256 + gsb * 8];
            }
#pragma unroll
            for (int mi = 0; mi < 2; mi++)
#pragma unroll
                for (int ni = 0; ni < 2; ni++)
                    acc[mi][ni] = __builtin_amdgcn_mfma_f32_16x16x32_bf16(
                        a[mi], b[ni], acc[mi][ni], 0, 0, 0);
            if (w0) {
#pragma unroll
                for (int mi = 0; mi < 2; mi++)
                    accE[mi] = __builtin_amdgcn_mfma_f32_16x16x32_bf16(
                        a[mi], ereg[kk], accE[mi], 0, 0, 0);
            }
        }

        // ---- epilogue. C/D: col = lane&15, row = 4*(lane>>4)+reg ----
        int bm = t * 32;
#pragma unroll
        for (int mi = 0; mi < 2; mi++) {
#pragma unroll
            for (int reg = 0; reg < 4; reg++) {
                int r = bm + mi * 16 + lg * 4 + reg;
                bool valid = (r < N);
                int rr = valid ? r : 0;
                if (isH) {
                    float nrm = rsqrtf(fmaxf((float)out_cnt[rr], 1.0f));
                    if (valid) {
#pragma unroll
                        for (int ni = 0; ni < 2; ni++)
                            h16[(size_t)r * HD + colloc + ni * 16 + l15] =
                                f2bf(acc[mi][ni][reg] * nrm);
                        if (w0) {
                            float ev = accE[mi][reg];  // l15<4: el, 4..7: er
                            if (l15 < 4) el[r * 4 + l15] = ev * nrm;
                            else if (l15 < 8) er[r * 4 + (l15 - 4)] = ev;
                        }
                    }
                } else if (valid) {
#pragma unroll
                    for (int ni = 0; ni < 2; ni++)
                        resid16[(size_t)r * HD + colloc + ni * 16 + l15] =
                            f2bf(acc[mi][ni][reg]);
                }
            }
        }
    }
}

// ---------------- fused edge softmax + weighted scatter + final ----------------
// One wave per dst node, lane-transposed: 64 lanes = 4 edge-slots x 16 dim-lanes.
// 16-edge chunks (4 sub-edges per lane) with 2-stage pipeline -> 16 gathers in
// flight. Final write = sc*acc + resid16 (out written exactly once).
__global__ __launch_bounds__(256) void agg_kernel(const unsigned short* __restrict__ h16,
                                                  const float* __restrict__ el,
                                                  const float* __restrict__ er,
                                                  const int* __restrict__ row_start,
                                                  const int* __restrict__ esrc,
                                                  const unsigned short* __restrict__ resid16,
                                                  float* __restrict__ out, int N) {
    int wid = threadIdx.x >> 6, lane = threadIdx.x & 63;
    int n = blockIdx.x * 4 + wid;
    if (n >= N) return;
    int es = lane >> 4;        // edge slot 0..3
    int l15 = lane & 15;
    int h = l15 >> 2;          // head owning this lane's 8 dims
    int d0 = l15 * 8;
    int beg = row_start[n], end = row_start[n + 1];
    float erh = er[n * 4 + h];
    float den = 0.f;
    float acc[8];
#pragma unroll
    for (int j = 0; j < 8; j++) acc[j] = 0.f;

    if (beg < end) {
        bool ok[4]; float ev[4]; short8 hv[4];
        auto LOAD = [&](int base, bool* okk, float* evv, short8* hvv) {
#pragma unroll
            for (int u = 0; u < 4; u++) {
                int idx = base + u * 4 + es;
                okk[u] = idx < end;
                int s = esrc[okk[u] ? idx : beg];
                evv[u] = el[s * 4 + h];
                hvv[u] = *(const short8*)(h16 + (size_t)s * HD + d0);
            }
        };
        auto COMPUTE = [&](const bool* okk, const float* evv, const short8* hvv) {
#pragma unroll
            for (int u = 0; u < 4; u++) {
                float e = evv[u] + erh;
                e = (e > 0.f) ? e : NEG_SLOPE * e;
                float ex = okk[u] ? __expf(e) : 0.f;
                den += ex;
#pragma unroll
                for (int j = 0; j < 8; j++)
                    acc[j] += ex * bf2f((unsigned short)hvv[u][j]);
            }
        };
        LOAD(beg, ok, ev, hv);
        for (int base = beg + 16; base < end; base += 16) {
            bool ok2[4]; float ev2[4]; short8 hv2[4];
            LOAD(base, ok2, ev2, hv2);
            COMPUTE(ok, ev, hv);
#pragma unroll
            for (int u = 0; u < 4; u++) { ok[u] = ok2[u]; ev[u] = ev2[u]; hv[u] = hv2[u]; }
        }
        COMPUTE(ok, ev, hv);
    }

    // reduce over the 4 edge slots (lanes differing in bits 4,5)
#pragma unroll
    for (int m = 16; m < 64; m <<= 1) {
        den += __shfl_xor(den, m);
#pragma unroll
        for (int j = 0; j < 8; j++) acc[j] += __shfl_xor(acc[j], m);
    }

    if (es == 0) {
        const unsigned short* rp = resid16 + (size_t)n * HD + d0;
        short8 rv = *(const short8*)rp;
        int indeg = end - beg;
        float sc = (indeg > 0) ? sqrtf((float)indeg) / den : 0.f;
        float o[8];
#pragma unroll
        for (int j = 0; j < 8; j++)
            o[j] = sc * acc[j] + bf2f((unsigned short)rv[j]);
        float* op = out + (size_t)n * HD + d0;
        *(float4*)op = make_float4(o[0], o[1], o[2], o[3]);
        *(float4*)(op + 4) = make_float4(o[4], o[5], o[6], o[7]);
    }
}

extern "C" void kernel_launch(void* const* d_in, const int* in_sizes, int n_in,
                              void* d_out, int out_size, void* d_ws, size_t ws_size,
                              hipStream_t stream) {
    const float* feat   = (const float*)d_in[0];
    const int*   src    = (const int*)d_in[1];
    const int*   dst    = (const int*)d_in[2];
    const float* W_fc   = (const float*)d_in[3];
    const float* attn_l = (const float*)d_in[4];
    const float* attn_r = (const float*)d_in[5];
    const float* W_res  = (const float*)d_in[6];
    float* out = (float*)d_out;

    int N = in_sizes[0] / IN_F;   // 50000
    int E = in_sizes[1];          // 800000
    int nb = (N + 255) / 256;     // 196 (<= 256 for scan3's internal scan)

    size_t off = 0;
    auto alloc = [&](size_t bytes) {
        size_t o = off;
        off = (off + bytes + 255) & ~(size_t)255;
        return o;
    };
    char* ws = (char*)d_ws;
    unsigned short* h16     = (unsigned short*)(ws + alloc((size_t)N * HD * 2));
    unsigned short* resid16 = (unsigned short*)(ws + alloc((size_t)N * HD * 2));
    __hip_bfloat16* w16     = (__hip_bfloat16*)(ws + alloc((size_t)2 * HD * IN_F * 2));
    unsigned short* ew16    = (unsigned short*)(ws + alloc((size_t)16 * IN_F * 2));
    float* el               = (float*)(ws + alloc((size_t)N * 4 * 4));
    float* er               = (float*)(ws + alloc((size_t)N * 4 * 4));
    int* out_cnt            = (int*)(ws + alloc((size_t)N * 4));
    int* deg                = (int*)(ws + alloc((size_t)N * 4));
    int* row_start          = (int*)(ws + alloc((size_t)(N + 1) * 4));
    int* bsum               = (int*)(ws + alloc((size_t)nb * 4));
    int* esrc               = (int*)(ws + alloc((size_t)E * 4));
    unsigned short* pc_src  = (unsigned short*)(ws + alloc((size_t)CSRC * N * 2));

    // runtime-adaptive dst-chunk count (each chunk = one uint16 row of N)
    size_t per_chunk = (size_t)2 * N;
    size_t avail = (ws_size > off + 4096) ? (ws_size - off - 4096) : 0;
    int C = (int)(avail / per_chunk);
    if (C > 128) C = 128;
    if (C < 32) C = 32;
    unsigned short* pc_dst = (unsigned short*)(ws + alloc((size_t)C * N * 2));
    int chunk = (E + C - 1) / C;
    int chunk_s = (E + CSRC - 1) / CSRC;

    int n4each = HD * IN_F / 4;
    int cvtb = (2 * n4each + 255) / 256;
    cvt_ew_kernel<<<4 + cvtb, 256, 0, stream>>>(
        (const float4*)W_fc, (const float4*)W_res, W_fc, attn_l, attn_r,
        (ushort4*)w16, ew16, n4each);

    hist_kernel<<<C + CSRC, 512, 0, stream>>>(src, dst, pc_src, pc_dst,
                                              N, E, C, chunk, chunk_s);
    sum_scan1_kernel<<<nb, 256, 0, stream>>>(pc_src, pc_dst, out_cnt, deg, bsum, N, C);
    scan3_kernel<<<nb, 256, 0, stream>>>(deg, bsum, row_start, N, nb, E);
    place_kernel<<<C, 512, 0, stream>>>(src, dst, pc_dst, row_start, esrc, N, E, chunk);

    int ntiles = (N + 31) / 32;
    gemm_fused<<<GGRID, 512, 0, stream>>>(feat, (const __hip_bfloat16*)w16,
                                          (const __hip_bfloat16*)ew16, out_cnt,
                                          h16, resid16, el, er, N, ntiles);

    int nb4 = (N + 3) / 4;
    agg_kernel<<<nb4, 256, 0, stream>>>(h16, el, er, row_start, esrc, resid16, out, N);
}

// Round 16
// 141.462 us; speedup vs baseline: 1.0510x; 1.0510x over previous
//
#include <hip/hip_runtime.h>
#include <hip/hip_bf16.h>
#include <math.h>

#define HD 128          // N_HEADS * OUT_FEATS
#define IN_F 256
#define NEG_SLOPE 0.2f
#define NMAX 50000      // problem-fixed node count (LDS histogram capacity)
#define GGRID 256       // persistent gemm grid (1 block/CU, 16 waves)
#define CSRC 32         // src-histogram chunk count (only totals needed)

typedef __attribute__((ext_vector_type(8))) short short8;
typedef __attribute__((ext_vector_type(4))) float f32x4;

__device__ __forceinline__ unsigned short f2bf(float x) {
    __hip_bfloat16 b = __float2bfloat16(x);
    return *(unsigned short*)&b;
}
__device__ __forceinline__ float bf2f(unsigned short u) {
    unsigned int v = ((unsigned int)u) << 16;
    float f;
    __builtin_memcpy(&f, &v, 4);
    return f;
}
__device__ __forceinline__ short8 pack8(float4 f0, float4 f1) {
    short8 v;
    v[0] = (short)f2bf(f0.x); v[1] = (short)f2bf(f0.y);
    v[2] = (short)f2bf(f0.z); v[3] = (short)f2bf(f0.w);
    v[4] = (short)f2bf(f1.x); v[5] = (short)f2bf(f1.y);
    v[6] = (short)f2bf(f1.z); v[7] = (short)f2bf(f1.w);
    return v;
}

// ---------------- weights f32->bf16 + ew columns, fused ----------------
// blocks 0..3: ew rows for head b; blocks 4..: w16 conversion.
__global__ __launch_bounds__(256) void cvt_ew_kernel(
    const float4* __restrict__ wfc4, const float4* __restrict__ wres4,
    const float* __restrict__ wfc, const float* __restrict__ attn_l,
    const float* __restrict__ attn_r, ushort4* __restrict__ w16,
    unsigned short* __restrict__ ew16, int n4each) {
    int b = blockIdx.x;
    if (b < 4) {
        int h = b, k = threadIdx.x;
        float sl = 0.f, sr = 0.f;
#pragma unroll 8
        for (int d = 0; d < 32; d++) {
            float w = wfc[(size_t)(h * 32 + d) * IN_F + k];
            sl += attn_l[h * 32 + d] * w;
            sr += attn_r[h * 32 + d] * w;
        }
        ew16[h * IN_F + k] = f2bf(sl);
        ew16[(4 + h) * IN_F + k] = f2bf(sr);
        ew16[(8 + h) * IN_F + k] = 0;
        ew16[(12 + h) * IN_F + k] = 0;
        return;
    }
    int idx = (b - 4) * 256 + threadIdx.x;
    if (idx >= 2 * n4each) return;
    float4 f = (idx < n4each) ? wfc4[idx] : wres4[idx - n4each];
    ushort4 u;
    u.x = f2bf(f.x); u.y = f2bf(f.y); u.z = f2bf(f.z); u.w = f2bf(f.w);
    w16[idx] = u;
}

// ---------------- per-chunk LDS histogram (uint16-packed, no global atomics) ----
// blocks 0..C-1: dst chunks (size chunk); blocks C..C+CSRC-1: src chunks (chunk_s).
__global__ __launch_bounds__(1024) void hist_kernel(const int* __restrict__ src,
                                                    const int* __restrict__ dst,
                                                    unsigned short* __restrict__ pc_src,
                                                    unsigned short* __restrict__ pc_dst,
                                                    int N, int E, int C, int chunk,
                                                    int chunk_s) {
    __shared__ unsigned int h[NMAX / 2];   // 100 KB packed uint16 counts
    int tid = threadIdx.x;
    int nh = N >> 1;                        // N even
    uint4* h4 = (uint4*)h;
    for (int i = tid; i < (nh >> 2); i += 1024) h4[i] = make_uint4(0, 0, 0, 0);
    for (int i = (nh & ~3) + tid; i < nh; i += 1024) h[i] = 0;
    __syncthreads();

    int b = blockIdx.x;
    bool isSrc = (b >= C);
    const int* arr = isSrc ? src : dst;
    int c = isSrc ? (b - C) : b;
    int ch = isSrc ? chunk_s : chunk;
    int e0 = c * ch, e1 = min(E, (c + 1) * ch);
    for (int e = e0 + tid; e < e1; e += 1024) {
        int v = arr[e];
        atomicAdd(&h[v >> 1], 1u << ((v & 1) << 4));
    }
    __syncthreads();

    unsigned short* pc = (isSrc ? pc_src : pc_dst) + (size_t)c * N;
    uint4* pc4 = (uint4*)pc;
    for (int i = tid; i < (nh >> 2); i += 1024) pc4[i] = h4[i];
    for (int i = (nh & ~3) + tid; i < nh; i += 1024) ((unsigned int*)pc)[i] = h[i];
}

// ---------------- per-node chunk prefix (in place) + degrees + scan1 ----------------
__global__ __launch_bounds__(256) void sum_scan1_kernel(
    const unsigned short* __restrict__ pc_src, unsigned short* __restrict__ pc_dst,
    int* __restrict__ out_cnt, int* __restrict__ deg, int* __restrict__ bsum,
    int N, int C) {
    __shared__ int wsum[4];
    int n = blockIdx.x * 256 + threadIdx.x;
    int sd = 0;
    if (n < N) {
        int ss = 0;
#pragma unroll 4
        for (int c = 0; c < CSRC; c++) ss += pc_src[(size_t)c * N + n];
        for (int c = 0; c < C; c++) {
            unsigned short v = pc_dst[(size_t)c * N + n];
            pc_dst[(size_t)c * N + n] = (unsigned short)sd;  // exclusive chunk prefix
            sd += v;
        }
        out_cnt[n] = ss;
        deg[n] = sd;
    }
    int v = (n < N) ? sd : 0;
#pragma unroll
    for (int d = 1; d < 64; d <<= 1) v += __shfl_xor(v, d);
    if ((threadIdx.x & 63) == 0) wsum[threadIdx.x >> 6] = v;
    __syncthreads();
    if (threadIdx.x == 0) bsum[blockIdx.x] = wsum[0] + wsum[1] + wsum[2] + wsum[3];
}

// ---------------- scan3 with internal block-sum scan (absorbs old scan2) ----------
__global__ __launch_bounds__(256) void scan3_kernel(const int* __restrict__ deg,
                                                    const int* __restrict__ bsum,
                                                    int* __restrict__ row_start,
                                                    int N, int nb, int E) {
    __shared__ int wsum[4];
    __shared__ int sbo[256];
    int tid = threadIdx.x, lane = tid & 63, wid = tid >> 6;
    // --- internal scan of bsum (nb <= 256) ---
    {
        int v = (tid < nb) ? bsum[tid] : 0;
        int incl = v;
#pragma unroll
        for (int d = 1; d < 64; d <<= 1) {
            int t = __shfl_up(incl, d);
            if (lane >= d) incl += t;
        }
        if (lane == 63) wsum[wid] = incl;
        __syncthreads();
        int woff = 0;
        for (int w = 0; w < wid; w++) woff += wsum[w];
        sbo[tid] = woff + incl - v;    // exclusive prefix of block sums
        __syncthreads();
    }
    int boff = sbo[blockIdx.x];
    if (blockIdx.x == 0 && tid == 0) row_start[N] = E;
    __syncthreads();

    int i = blockIdx.x * 256 + tid;
    int v = (i < N) ? deg[i] : 0;
    int incl = v;
#pragma unroll
    for (int d = 1; d < 64; d <<= 1) {
        int t = __shfl_up(incl, d);
        if (lane >= d) incl += t;
    }
    if (lane == 63) wsum[wid] = incl;
    __syncthreads();
    int woff = 0;
    for (int w = 0; w < wid; w++) woff += wsum[w];
    int excl = boff + woff + incl - v;
    if (i < N) row_start[i] = excl;
}

// ---------------- placement: LDS cursors seeded from chunk prefix ----------------
__global__ __launch_bounds__(1024) void place_kernel(const int* __restrict__ src,
                                                     const int* __restrict__ dst,
                                                     const unsigned short* __restrict__ chunkpre,
                                                     const int* __restrict__ row_start,
                                                     int* __restrict__ esrc,
                                                     int N, int E, int chunk) {
    __shared__ unsigned int cur[NMAX / 2];   // packed uint16 cursors
    int tid = threadIdx.x;
    int nh = N >> 1;
    const unsigned short* cp = chunkpre + (size_t)blockIdx.x * N;
    const uint4* cp4 = (const uint4*)cp;
    uint4* cur4 = (uint4*)cur;
    for (int i = tid; i < (nh >> 2); i += 1024) cur4[i] = cp4[i];
    for (int i = (nh & ~3) + tid; i < nh; i += 1024) cur[i] = ((const unsigned int*)cp)[i];
    __syncthreads();

    int e1 = min(E, (int)(blockIdx.x + 1) * chunk);
    for (int e = blockIdx.x * chunk + tid; e < e1; e += 1024) {
        int d = dst[e], s = src[e];
        int sh = (d & 1) << 4;
        unsigned int old = atomicAdd(&cur[d >> 1], 1u << sh);
        int rank = (old >> sh) & 0xffff;
        esrc[row_start[d] + rank] = s;
    }
}

// ---------------- persistent fused GEMM: B in LDS, 16 waves for latency hiding ----
// 256 blocks x 16 waves (1024 thr, 4 waves/SIMD). sB = full 256x256 bf16 weight
// panel (128 KiB, staged once, XOR-swizzled). Per 32-row tile: reg-prefetch f32
// A -> cvt -> sA (16 KiB) -> pure ds_read+MFMA. Wave w owns cols w*16..+15;
// waves 0-7 write h16 (+norm), 8-15 write resid16; wave 0 adds el/er via ew16.
__global__ __launch_bounds__(1024, 1) void gemm_fused(
    const float* __restrict__ feat, const __hip_bfloat16* __restrict__ w16,
    const __hip_bfloat16* __restrict__ ew16, const int* __restrict__ out_cnt,
    unsigned short* __restrict__ h16, unsigned short* __restrict__ resid16,
    float* __restrict__ el, float* __restrict__ er, int N, int ntiles) {
    __shared__ unsigned short sB[256 * 256];  // 128 KiB
    __shared__ unsigned short sA[32 * 256];   // 16 KiB
    int tid = threadIdx.x;
    int lane = tid & 63, w = tid >> 6;        // 16 waves
    int l15 = lane & 15, lg = lane >> 4;
    int c0 = w * 16;
    bool w0 = (w == 0);
    bool isH = (w < 8);
    int colloc = c0 & 127;

    // ---- stage B once: 8192 granules (8 per thread), XOR-swizzled by col ----
#pragma unroll
    for (int it = 0; it < 8; ++it) {
        int idx = it * 1024 + tid;
        int c = idx >> 5, g = idx & 31;
        short8 v = *(const short8*)(w16 + (size_t)c * IN_F + g * 8);
        *(short8*)&sB[c * 256 + ((g ^ (c & 7)) * 8)] = v;
    }
    // ew fragment for wave 0 (8 short8 regs)
    short8 ereg[8];
    if (w0) {
        const __hip_bfloat16* ep = ew16 + (size_t)l15 * IN_F + lg * 8;
#pragma unroll
        for (int kk = 0; kk < 8; kk++) ereg[kk] = *(const short8*)(ep + kk * 32);
    }

    // A-stage mapping: exactly one granule per thread
    int srow = tid >> 5, sgc = tid & 31;

    float4 fA0, fA1;
    int t = blockIdx.x;
    {
        int gm = t * 32 + srow;
        gm = (gm < N) ? gm : (N - 1);
        const float4* fp = (const float4*)(feat + (size_t)gm * IN_F + sgc * 8);
        fA0 = fp[0];
        fA1 = fp[1];
    }

    for (; t < ntiles; t += GGRID) {
        __syncthreads();   // all waves done reading sA (and, first iter, sB staged)
        *(short8*)&sA[srow * 256 + ((sgc ^ (srow & 7)) * 8)] = pack8(fA0, fA1);
        __syncthreads();   // sA staged

        // ---- issue next tile's loads (latency hides under k-loop + epilogue) ----
        int tn = t + GGRID;
        if (tn < ntiles) {
            int gm = tn * 32 + srow;
            gm = (gm < N) ? gm : (N - 1);
            const float4* fp = (const float4*)(feat + (size_t)gm * IN_F + sgc * 8);
            fA0 = fp[0];
            fA1 = fp[1];
        }

        // ---- k-loop: pure LDS reads + MFMA ----
        f32x4 acc[2], accE[2];
#pragma unroll
        for (int i = 0; i < 2; i++) {
            acc[i] = (f32x4){0.f, 0.f, 0.f, 0.f};
            accE[i] = (f32x4){0.f, 0.f, 0.f, 0.f};
        }
#pragma unroll
        for (int kk = 0; kk < 8; kk++) {
            short8 a[2], b;
#pragma unroll
            for (int mi = 0; mi < 2; mi++) {
                int row = mi * 16 + l15;
                int gs = (kk * 4 + lg) ^ (row & 7);
                a[mi] = *(const short8*)&sA[row * 256 + gs * 8];
            }
            {
                int c = c0 + l15;
                int gsb = (kk * 4 + lg) ^ (c & 7);
                b = *(const short8*)&sB[c * 256 + gsb * 8];
            }
#pragma unroll
            for (int mi = 0; mi < 2; mi++)
                acc[mi] = __builtin_amdgcn_mfma_f32_16x16x32_bf16(a[mi], b, acc[mi],
                                                                  0, 0, 0);
            if (w0) {
#pragma unroll
                for (int mi = 0; mi < 2; mi++)
                    accE[mi] = __builtin_amdgcn_mfma_f32_16x16x32_bf16(
                        a[mi], ereg[kk], accE[mi], 0, 0, 0);
            }
        }

        // ---- epilogue. C/D: col = lane&15, row = 4*(lane>>4)+reg ----
        int bm = t * 32;
#pragma unroll
        for (int mi = 0; mi < 2; mi++) {
#pragma unroll
            for (int reg = 0; reg < 4; reg++) {
                int r = bm + mi * 16 + lg * 4 + reg;
                bool valid = (r < N);
                int rr = valid ? r : 0;
                if (isH) {
                    float nrm = rsqrtf(fmaxf((float)out_cnt[rr], 1.0f));
                    if (valid) {
                        h16[(size_t)r * HD + colloc + l15] =
                            f2bf(acc[mi][reg] * nrm);
                        if (w0) {
                            float ev = accE[mi][reg];  // l15<4: el, 4..7: er
                            if (l15 < 4) el[r * 4 + l15] = ev * nrm;
                            else if (l15 < 8) er[r * 4 + (l15 - 4)] = ev;
                        }
                    }
                } else if (valid) {
                    resid16[(size_t)r * HD + colloc + l15] = f2bf(acc[mi][reg]);
                }
            }
        }
    }
}

// ---------------- fused edge softmax + weighted scatter + final ----------------
// One wave per dst node, lane-transposed: 64 lanes = 4 edge-slots x 16 dim-lanes.
// 8-edge chunks, 2-stage software pipeline. Final write = sc*acc + resid16.
__global__ __launch_bounds__(256) void agg_kernel(const unsigned short* __restrict__ h16,
                                                  const float* __restrict__ el,
                                                  const float* __restrict__ er,
                                                  const int* __restrict__ row_start,
                                                  const int* __restrict__ esrc,
                                                  const unsigned short* __restrict__ resid16,
                                                  float* __restrict__ out, int N) {
    int wid = threadIdx.x >> 6, lane = threadIdx.x & 63;
    int n = blockIdx.x * 4 + wid;
    if (n >= N) return;
    int es = lane >> 4;        // edge slot 0..3
    int l15 = lane & 15;
    int h = l15 >> 2;          // head owning this lane's 8 dims
    int d0 = l15 * 8;
    int beg = row_start[n], end = row_start[n + 1];
    float erh = er[n * 4 + h];
    float den = 0.f;
    float acc[8];
#pragma unroll
    for (int j = 0; j < 8; j++) acc[j] = 0.f;

    if (beg < end) {
        bool ok0, ok1;
        float ev0, ev1; short8 hv0, hv1;
        {
            int i0 = beg + es, i1 = beg + 4 + es;
            ok0 = i0 < end; ok1 = i1 < end;
            int s0 = esrc[ok0 ? i0 : beg];
            int s1 = esrc[ok1 ? i1 : beg];
            ev0 = el[s0 * 4 + h]; ev1 = el[s1 * 4 + h];
            hv0 = *(const short8*)(h16 + (size_t)s0 * HD + d0);
            hv1 = *(const short8*)(h16 + (size_t)s1 * HD + d0);
        }
        for (int base = beg + 8; base < end; base += 8) {
            int i0 = base + es, i1 = base + 4 + es;
            bool p0 = i0 < end, p1 = i1 < end;
            int t0 = esrc[p0 ? i0 : beg];
            int t1 = esrc[p1 ? i1 : beg];
            float fv0 = el[t0 * 4 + h];
            float fv1 = el[t1 * 4 + h];
            short8 g0 = *(const short8*)(h16 + (size_t)t0 * HD + d0);
            short8 g1 = *(const short8*)(h16 + (size_t)t1 * HD + d0);
            float e0 = ev0 + erh; e0 = (e0 > 0.f) ? e0 : NEG_SLOPE * e0;
            float e1 = ev1 + erh; e1 = (e1 > 0.f) ? e1 : NEG_SLOPE * e1;
            float ex0 = ok0 ? __expf(e0) : 0.f;
            float ex1 = ok1 ? __expf(e1) : 0.f;
            den += ex0 + ex1;
#pragma unroll
            for (int j = 0; j < 8; j++)
                acc[j] += ex0 * bf2f((unsigned short)hv0[j]) +
                          ex1 * bf2f((unsigned short)hv1[j]);
            ok0 = p0; ok1 = p1; ev0 = fv0; ev1 = fv1; hv0 = g0; hv1 = g1;
        }
        float e0 = ev0 + erh; e0 = (e0 > 0.f) ? e0 : NEG_SLOPE * e0;
        float e1 = ev1 + erh; e1 = (e1 > 0.f) ? e1 : NEG_SLOPE * e1;
        float ex0 = ok0 ? __expf(e0) : 0.f;
        float ex1 = ok1 ? __expf(e1) : 0.f;
        den += ex0 + ex1;
#pragma unroll
        for (int j = 0; j < 8; j++)
            acc[j] += ex0 * bf2f((unsigned short)hv0[j]) +
                      ex1 * bf2f((unsigned short)hv1[j]);
    }

    // reduce over the 4 edge slots (lanes differing in bits 4,5)
#pragma unroll
    for (int m = 16; m < 64; m <<= 1) {
        den += __shfl_xor(den, m);
#pragma unroll
        for (int j = 0; j < 8; j++) acc[j] += __shfl_xor(acc[j], m);
    }

    if (es == 0) {
        const unsigned short* rp = resid16 + (size_t)n * HD + d0;
        short8 rv = *(const short8*)rp;
        int indeg = end - beg;
        float sc = (indeg > 0) ? sqrtf((float)indeg) / den : 0.f;
        float o[8];
#pragma unroll
        for (int j = 0; j < 8; j++)
            o[j] = sc * acc[j] + bf2f((unsigned short)rv[j]);
        float* op = out + (size_t)n * HD + d0;
        *(float4*)op = make_float4(o[0], o[1], o[2], o[3]);
        *(float4*)(op + 4) = make_float4(o[4], o[5], o[6], o[7]);
    }
}

extern "C" void kernel_launch(void* const* d_in, const int* in_sizes, int n_in,
                              void* d_out, int out_size, void* d_ws, size_t ws_size,
                              hipStream_t stream) {
    const float* feat   = (const float*)d_in[0];
    const int*   src    = (const int*)d_in[1];
    const int*   dst    = (const int*)d_in[2];
    const float* W_fc   = (const float*)d_in[3];
    const float* attn_l = (const float*)d_in[4];
    const float* attn_r = (const float*)d_in[5];
    const float* W_res  = (const float*)d_in[6];
    float* out = (float*)d_out;

    int N = in_sizes[0] / IN_F;   // 50000
    int E = in_sizes[1];          // 800000
    int nb = (N + 255) / 256;     // 196 (<= 256 for scan3's internal scan)

    size_t off = 0;
    auto alloc = [&](size_t bytes) {
        size_t o = off;
        off = (off + bytes + 255) & ~(size_t)255;
        return o;
    };
    char* ws = (char*)d_ws;
    unsigned short* h16     = (unsigned short*)(ws + alloc((size_t)N * HD * 2));
    unsigned short* resid16 = (unsigned short*)(ws + alloc((size_t)N * HD * 2));
    __hip_bfloat16* w16     = (__hip_bfloat16*)(ws + alloc((size_t)2 * HD * IN_F * 2));
    unsigned short* ew16    = (unsigned short*)(ws + alloc((size_t)16 * IN_F * 2));
    float* el               = (float*)(ws + alloc((size_t)N * 4 * 4));
    float* er               = (float*)(ws + alloc((size_t)N * 4 * 4));
    int* out_cnt            = (int*)(ws + alloc((size_t)N * 4));
    int* deg                = (int*)(ws + alloc((size_t)N * 4));
    int* row_start          = (int*)(ws + alloc((size_t)(N + 1) * 4));
    int* bsum               = (int*)(ws + alloc((size_t)nb * 4));
    int* esrc               = (int*)(ws + alloc((size_t)E * 4));
    unsigned short* pc_src  = (unsigned short*)(ws + alloc((size_t)CSRC * N * 2));

    // runtime-adaptive dst-chunk count (each chunk = one uint16 row of N)
    size_t per_chunk = (size_t)2 * N;
    size_t avail = (ws_size > off + 4096) ? (ws_size - off - 4096) : 0;
    int C = (int)(avail / per_chunk);
    if (C > 128) C = 128;
    if (C < 32) C = 32;
    unsigned short* pc_dst = (unsigned short*)(ws + alloc((size_t)C * N * 2));
    int chunk = (E + C - 1) / C;
    int chunk_s = (E + CSRC - 1) / CSRC;

    int n4each = HD * IN_F / 4;
    int cvtb = (2 * n4each + 255) / 256;
    cvt_ew_kernel<<<4 + cvtb, 256, 0, stream>>>(
        (const float4*)W_fc, (const float4*)W_res, W_fc, attn_l, attn_r,
        (ushort4*)w16, ew16, n4each);

    hist_kernel<<<C + CSRC, 1024, 0, stream>>>(src, dst, pc_src, pc_dst,
                                               N, E, C, chunk, chunk_s);
    sum_scan1_kernel<<<nb, 256, 0, stream>>>(pc_src, pc_dst, out_cnt, deg, bsum, N, C);
    scan3_kernel<<<nb, 256, 0, stream>>>(deg, bsum, row_start, N, nb, E);
    place_kernel<<<C, 1024, 0, stream>>>(src, dst, pc_dst, row_start, esrc, N, E, chunk);

    int ntiles = (N + 31) / 32;
    gemm_fused<<<GGRID, 1024, 0, stream>>>(feat, (const __hip_bfloat16*)w16,
                                           (const __hip_bfloat16*)ew16, out_cnt,
                                           h16, resid16, el, er, N, ntiles);

    int nb4 = (N + 3) / 4;
    agg_kernel<<<nb4, 256, 0, stream>>>(h16, el, er, row_start, esrc, resid16, out, N);
}

// Round 17
// 133.178 us; speedup vs baseline: 1.1164x; 1.0622x over previous
//
#include <hip/hip_runtime.h>
#include <hip/hip_bf16.h>
#include <math.h>

#define HD 128          // N_HEADS * OUT_FEATS
#define IN_F 256
#define NEG_SLOPE 0.2f
#define NMAX 50000      // problem-fixed node count (LDS histogram capacity)
#define GGRID 256       // persistent gemm grid partition (16 waves each)
#define CSRC 32         // src-histogram chunk count (only totals needed)

typedef __attribute__((ext_vector_type(8))) short short8;
typedef __attribute__((ext_vector_type(4))) float f32x4;

__device__ __forceinline__ unsigned short f2bf(float x) {
    __hip_bfloat16 b = __float2bfloat16(x);
    return *(unsigned short*)&b;
}
__device__ __forceinline__ float bf2f(unsigned short u) {
    unsigned int v = ((unsigned int)u) << 16;
    float f;
    __builtin_memcpy(&f, &v, 4);
    return f;
}
__device__ __forceinline__ short8 pack8(float4 f0, float4 f1) {
    short8 v;
    v[0] = (short)f2bf(f0.x); v[1] = (short)f2bf(f0.y);
    v[2] = (short)f2bf(f0.z); v[3] = (short)f2bf(f0.w);
    v[4] = (short)f2bf(f1.x); v[5] = (short)f2bf(f1.y);
    v[6] = (short)f2bf(f1.z); v[7] = (short)f2bf(f1.w);
    return v;
}

// ======== K1: histograms + weight conversion + ew columns, one launch ========
// blocks [0..C)         : dst-chunk LDS histogram
// blocks [C..C+CSRC)    : src-chunk LDS histogram
// block  C+CSRC         : ew16 (4 heads x 256 cols, 1024 thr)
// blocks [C+CSRC+1 ..)  : w16 conversion (1024 ushort4 each)
__global__ __launch_bounds__(1024) void hist_cvt_kernel(
    const int* __restrict__ src, const int* __restrict__ dst,
    unsigned short* __restrict__ pc_src, unsigned short* __restrict__ pc_dst,
    const float4* __restrict__ wfc4, const float4* __restrict__ wres4,
    const float* __restrict__ wfc, const float* __restrict__ attn_l,
    const float* __restrict__ attn_r, ushort4* __restrict__ w16,
    unsigned short* __restrict__ ew16, int n4each,
    int N, int E, int C, int chunk, int chunk_s) {
    __shared__ unsigned int h[NMAX / 2];   // 100 KB packed uint16 counts
    int tid = threadIdx.x;
    int b = blockIdx.x;

    if (b >= C + CSRC) {
        int rb = b - C - CSRC;
        if (rb == 0) {
            // ew columns
            int hh = tid >> 8, k = tid & 255;
            float sl = 0.f, sr = 0.f;
#pragma unroll 8
            for (int d = 0; d < 32; d++) {
                float w = wfc[(size_t)(hh * 32 + d) * IN_F + k];
                sl += attn_l[hh * 32 + d] * w;
                sr += attn_r[hh * 32 + d] * w;
            }
            ew16[hh * IN_F + k] = f2bf(sl);
            ew16[(4 + hh) * IN_F + k] = f2bf(sr);
            ew16[(8 + hh) * IN_F + k] = 0;
            ew16[(12 + hh) * IN_F + k] = 0;
        } else {
            int idx = (rb - 1) * 1024 + tid;
            if (idx < 2 * n4each) {
                float4 f = (idx < n4each) ? wfc4[idx] : wres4[idx - n4each];
                ushort4 u;
                u.x = f2bf(f.x); u.y = f2bf(f.y); u.z = f2bf(f.z); u.w = f2bf(f.w);
                w16[idx] = u;
            }
        }
        return;
    }

    int nh = N >> 1;                        // N even
    uint4* h4 = (uint4*)h;
    for (int i = tid; i < (nh >> 2); i += 1024) h4[i] = make_uint4(0, 0, 0, 0);
    for (int i = (nh & ~3) + tid; i < nh; i += 1024) h[i] = 0;
    __syncthreads();

    bool isSrc = (b >= C);
    const int* arr = isSrc ? src : dst;
    int c = isSrc ? (b - C) : b;
    int ch = isSrc ? chunk_s : chunk;
    int e0 = c * ch, e1 = min(E, (c + 1) * ch);
    for (int e = e0 + tid; e < e1; e += 1024) {
        int v = arr[e];
        atomicAdd(&h[v >> 1], 1u << ((v & 1) << 4));
    }
    __syncthreads();

    unsigned short* pc = (isSrc ? pc_src : pc_dst) + (size_t)c * N;
    uint4* pc4 = (uint4*)pc;
    for (int i = tid; i < (nh >> 2); i += 1024) pc4[i] = h4[i];
    for (int i = (nh & ~3) + tid; i < nh; i += 1024) ((unsigned int*)pc)[i] = h[i];
}

// ---------------- per-node chunk prefix (in place) + degrees + scan1 ----------------
__global__ __launch_bounds__(256) void sum_scan1_kernel(
    const unsigned short* __restrict__ pc_src, unsigned short* __restrict__ pc_dst,
    int* __restrict__ out_cnt, int* __restrict__ deg, int* __restrict__ bsum,
    int N, int C) {
    __shared__ int wsum[4];
    int n = blockIdx.x * 256 + threadIdx.x;
    int sd = 0;
    if (n < N) {
        int ss = 0;
#pragma unroll 4
        for (int c = 0; c < CSRC; c++) ss += pc_src[(size_t)c * N + n];
        for (int c = 0; c < C; c++) {
            unsigned short v = pc_dst[(size_t)c * N + n];
            pc_dst[(size_t)c * N + n] = (unsigned short)sd;  // exclusive chunk prefix
            sd += v;
        }
        out_cnt[n] = ss;
        deg[n] = sd;
    }
    int v = (n < N) ? sd : 0;
#pragma unroll
    for (int d = 1; d < 64; d <<= 1) v += __shfl_xor(v, d);
    if ((threadIdx.x & 63) == 0) wsum[threadIdx.x >> 6] = v;
    __syncthreads();
    if (threadIdx.x == 0) bsum[blockIdx.x] = wsum[0] + wsum[1] + wsum[2] + wsum[3];
}

// ---------------- scan3 with internal block-sum scan ----------------
__global__ __launch_bounds__(256) void scan3_kernel(const int* __restrict__ deg,
                                                    const int* __restrict__ bsum,
                                                    int* __restrict__ row_start,
                                                    int N, int nb, int E) {
    __shared__ int wsum[4];
    __shared__ int sbo[256];
    int tid = threadIdx.x, lane = tid & 63, wid = tid >> 6;
    {
        int v = (tid < nb) ? bsum[tid] : 0;
        int incl = v;
#pragma unroll
        for (int d = 1; d < 64; d <<= 1) {
            int t = __shfl_up(incl, d);
            if (lane >= d) incl += t;
        }
        if (lane == 63) wsum[wid] = incl;
        __syncthreads();
        int woff = 0;
        for (int w = 0; w < wid; w++) woff += wsum[w];
        sbo[tid] = woff + incl - v;    // exclusive prefix of block sums
        __syncthreads();
    }
    int boff = sbo[blockIdx.x];
    if (blockIdx.x == 0 && tid == 0) row_start[N] = E;
    __syncthreads();

    int i = blockIdx.x * 256 + tid;
    int v = (i < N) ? deg[i] : 0;
    int incl = v;
#pragma unroll
    for (int d = 1; d < 64; d <<= 1) {
        int t = __shfl_up(incl, d);
        if (lane >= d) incl += t;
    }
    if (lane == 63) wsum[wid] = incl;
    __syncthreads();
    int woff = 0;
    for (int w = 0; w < wid; w++) woff += wsum[w];
    int excl = boff + woff + incl - v;
    if (i < N) row_start[i] = excl;
}

// ======== K3: placement + persistent GEMM, one launch (LDS union) ========
// blocks [0..C)       : place — LDS cursors seeded from chunk prefix
// blocks [C..C+GGRID) : persistent GEMM, 16 waves, B panel in LDS
__global__ __launch_bounds__(1024, 1) void place_gemm_kernel(
    const int* __restrict__ src, const int* __restrict__ dst,
    const unsigned short* __restrict__ chunkpre, const int* __restrict__ row_start,
    int* __restrict__ esrc,
    const float* __restrict__ feat, const __hip_bfloat16* __restrict__ w16,
    const __hip_bfloat16* __restrict__ ew16, const int* __restrict__ out_cnt,
    unsigned short* __restrict__ h16, unsigned short* __restrict__ resid16,
    float* __restrict__ el, float* __restrict__ er,
    int N, int E, int C, int chunk, int ntiles) {
    __shared__ __align__(16) char smem[147456];   // 144 KiB union
    int tid = threadIdx.x;

    if (blockIdx.x < C) {
        // ---------------- place partition ----------------
        unsigned int* cur = (unsigned int*)smem;   // 100 KB packed uint16 cursors
        int nh = N >> 1;
        const unsigned short* cp = chunkpre + (size_t)blockIdx.x * N;
        const uint4* cp4 = (const uint4*)cp;
        uint4* cur4 = (uint4*)cur;
        for (int i = tid; i < (nh >> 2); i += 1024) cur4[i] = cp4[i];
        for (int i = (nh & ~3) + tid; i < nh; i += 1024)
            cur[i] = ((const unsigned int*)cp)[i];
        __syncthreads();

        int e1 = min(E, (int)(blockIdx.x + 1) * chunk);
        for (int e = blockIdx.x * chunk + tid; e < e1; e += 1024) {
            int d = dst[e], s = src[e];
            int sh = (d & 1) << 4;
            unsigned int old = atomicAdd(&cur[d >> 1], 1u << sh);
            int rank = (old >> sh) & 0xffff;
            esrc[row_start[d] + rank] = s;
        }
        return;
    }

    // ---------------- gemm partition ----------------
    unsigned short* sB = (unsigned short*)smem;              // 128 KiB
    unsigned short* sA = (unsigned short*)(smem + 131072);   // 16 KiB
    int bid = blockIdx.x - C;
    int lane = tid & 63, w = tid >> 6;        // 16 waves
    int l15 = lane & 15, lg = lane >> 4;
    int c0 = w * 16;
    bool w0 = (w == 0);
    bool isH = (w < 8);
    int colloc = c0 & 127;

    // stage B once: 8192 granules (8 per thread), XOR-swizzled by col
#pragma unroll
    for (int it = 0; it < 8; ++it) {
        int idx = it * 1024 + tid;
        int c = idx >> 5, g = idx & 31;
        short8 v = *(const short8*)(w16 + (size_t)c * IN_F + g * 8);
        *(short8*)&sB[c * 256 + ((g ^ (c & 7)) * 8)] = v;
    }
    short8 ereg[8];
    if (w0) {
        const __hip_bfloat16* ep = ew16 + (size_t)l15 * IN_F + lg * 8;
#pragma unroll
        for (int kk = 0; kk < 8; kk++) ereg[kk] = *(const short8*)(ep + kk * 32);
    }

    int srow = tid >> 5, sgc = tid & 31;      // one A granule per thread
    float4 fA0, fA1;
    int t = bid;
    {
        int gm = t * 32 + srow;
        gm = (gm < N) ? gm : (N - 1);
        const float4* fp = (const float4*)(feat + (size_t)gm * IN_F + sgc * 8);
        fA0 = fp[0];
        fA1 = fp[1];
    }

    for (; t < ntiles; t += GGRID) {
        __syncthreads();   // all waves done reading sA (and, first iter, sB staged)
        *(short8*)&sA[srow * 256 + ((sgc ^ (srow & 7)) * 8)] = pack8(fA0, fA1);
        __syncthreads();   // sA staged

        int tn = t + GGRID;
        if (tn < ntiles) {
            int gm = tn * 32 + srow;
            gm = (gm < N) ? gm : (N - 1);
            const float4* fp = (const float4*)(feat + (size_t)gm * IN_F + sgc * 8);
            fA0 = fp[0];
            fA1 = fp[1];
        }

        f32x4 acc[2], accE[2];
#pragma unroll
        for (int i = 0; i < 2; i++) {
            acc[i] = (f32x4){0.f, 0.f, 0.f, 0.f};
            accE[i] = (f32x4){0.f, 0.f, 0.f, 0.f};
        }
#pragma unroll
        for (int kk = 0; kk < 8; kk++) {
            short8 a[2], b;
#pragma unroll
            for (int mi = 0; mi < 2; mi++) {
                int row = mi * 16 + l15;
                int gs = (kk * 4 + lg) ^ (row & 7);
                a[mi] = *(const short8*)&sA[row * 256 + gs * 8];
            }
            {
                int c = c0 + l15;
                int gsb = (kk * 4 + lg) ^ (c & 7);
                b = *(const short8*)&sB[c * 256 + gsb * 8];
            }
#pragma unroll
            for (int mi = 0; mi < 2; mi++)
                acc[mi] = __builtin_amdgcn_mfma_f32_16x16x32_bf16(a[mi], b, acc[mi],
                                                                  0, 0, 0);
            if (w0) {
#pragma unroll
                for (int mi = 0; mi < 2; mi++)
                    accE[mi] = __builtin_amdgcn_mfma_f32_16x16x32_bf16(
                        a[mi], ereg[kk], accE[mi], 0, 0, 0);
            }
        }

        int bm = t * 32;
#pragma unroll
        for (int mi = 0; mi < 2; mi++) {
#pragma unroll
            for (int reg = 0; reg < 4; reg++) {
                int r = bm + mi * 16 + lg * 4 + reg;
                bool valid = (r < N);
                int rr = valid ? r : 0;
                if (isH) {
                    float nrm = rsqrtf(fmaxf((float)out_cnt[rr], 1.0f));
                    if (valid) {
                        h16[(size_t)r * HD + colloc + l15] = f2bf(acc[mi][reg] * nrm);
                        if (w0) {
                            float ev = accE[mi][reg];  // l15<4: el, 4..7: er
                            if (l15 < 4) el[r * 4 + l15] = ev * nrm;
                            else if (l15 < 8) er[r * 4 + (l15 - 4)] = ev;
                        }
                    }
                } else if (valid) {
                    resid16[(size_t)r * HD + colloc + l15] = f2bf(acc[mi][reg]);
                }
            }
        }
    }
}

// ---------------- fused edge softmax + weighted scatter + final ----------------
// One wave per dst node, lane-transposed: 64 lanes = 4 edge-slots x 16 dim-lanes.
// 8-edge chunks, 2-stage software pipeline. Final write = sc*acc + resid16.
__global__ __launch_bounds__(256) void agg_kernel(const unsigned short* __restrict__ h16,
                                                  const float* __restrict__ el,
                                                  const float* __restrict__ er,
                                                  const int* __restrict__ row_start,
                                                  const int* __restrict__ esrc,
                                                  const unsigned short* __restrict__ resid16,
                                                  float* __restrict__ out, int N) {
    int wid = threadIdx.x >> 6, lane = threadIdx.x & 63;
    int n = blockIdx.x * 4 + wid;
    if (n >= N) return;
    int es = lane >> 4;        // edge slot 0..3
    int l15 = lane & 15;
    int h = l15 >> 2;          // head owning this lane's 8 dims
    int d0 = l15 * 8;
    int beg = row_start[n], end = row_start[n + 1];
    float erh = er[n * 4 + h];
    float den = 0.f;
    float acc[8];
#pragma unroll
    for (int j = 0; j < 8; j++) acc[j] = 0.f;

    if (beg < end) {
        bool ok0, ok1;
        float ev0, ev1; short8 hv0, hv1;
        {
            int i0 = beg + es, i1 = beg + 4 + es;
            ok0 = i0 < end; ok1 = i1 < end;
            int s0 = esrc[ok0 ? i0 : beg];
            int s1 = esrc[ok1 ? i1 : beg];
            ev0 = el[s0 * 4 + h]; ev1 = el[s1 * 4 + h];
            hv0 = *(const short8*)(h16 + (size_t)s0 * HD + d0);
            hv1 = *(const short8*)(h16 + (size_t)s1 * HD + d0);
        }
        for (int base = beg + 8; base < end; base += 8) {
            int i0 = base + es, i1 = base + 4 + es;
            bool p0 = i0 < end, p1 = i1 < end;
            int t0 = esrc[p0 ? i0 : beg];
            int t1 = esrc[p1 ? i1 : beg];
            float fv0 = el[t0 * 4 + h];
            float fv1 = el[t1 * 4 + h];
            short8 g0 = *(const short8*)(h16 + (size_t)t0 * HD + d0);
            short8 g1 = *(const short8*)(h16 + (size_t)t1 * HD + d0);
            float e0 = ev0 + erh; e0 = (e0 > 0.f) ? e0 : NEG_SLOPE * e0;
            float e1 = ev1 + erh; e1 = (e1 > 0.f) ? e1 : NEG_SLOPE * e1;
            float ex0 = ok0 ? __expf(e0) : 0.f;
            float ex1 = ok1 ? __expf(e1) : 0.f;
            den += ex0 + ex1;
#pragma unroll
            for (int j = 0; j < 8; j++)
                acc[j] += ex0 * bf2f((unsigned short)hv0[j]) +
                          ex1 * bf2f((unsigned short)hv1[j]);
            ok0 = p0; ok1 = p1; ev0 = fv0; ev1 = fv1; hv0 = g0; hv1 = g1;
        }
        float e0 = ev0 + erh; e0 = (e0 > 0.f) ? e0 : NEG_SLOPE * e0;
        float e1 = ev1 + erh; e1 = (e1 > 0.f) ? e1 : NEG_SLOPE * e1;
        float ex0 = ok0 ? __expf(e0) : 0.f;
        float ex1 = ok1 ? __expf(e1) : 0.f;
        den += ex0 + ex1;
#pragma unroll
        for (int j = 0; j < 8; j++)
            acc[j] += ex0 * bf2f((unsigned short)hv0[j]) +
                      ex1 * bf2f((unsigned short)hv1[j]);
    }

    // reduce over the 4 edge slots (lanes differing in bits 4,5)
#pragma unroll
    for (int m = 16; m < 64; m <<= 1) {
        den += __shfl_xor(den, m);
#pragma unroll
        for (int j = 0; j < 8; j++) acc[j] += __shfl_xor(acc[j], m);
    }

    if (es == 0) {
        const unsigned short* rp = resid16 + (size_t)n * HD + d0;
        short8 rv = *(const short8*)rp;
        int indeg = end - beg;
        float sc = (indeg > 0) ? sqrtf((float)indeg) / den : 0.f;
        float o[8];
#pragma unroll
        for (int j = 0; j < 8; j++)
            o[j] = sc * acc[j] + bf2f((unsigned short)rv[j]);
        float* op = out + (size_t)n * HD + d0;
        *(float4*)op = make_float4(o[0], o[1], o[2], o[3]);
        *(float4*)(op + 4) = make_float4(o[4], o[5], o[6], o[7]);
    }
}

extern "C" void kernel_launch(void* const* d_in, const int* in_sizes, int n_in,
                              void* d_out, int out_size, void* d_ws, size_t ws_size,
                              hipStream_t stream) {
    const float* feat   = (const float*)d_in[0];
    const int*   src    = (const int*)d_in[1];
    const int*   dst    = (const int*)d_in[2];
    const float* W_fc   = (const float*)d_in[3];
    const float* attn_l = (const float*)d_in[4];
    const float* attn_r = (const float*)d_in[5];
    const float* W_res  = (const float*)d_in[6];
    float* out = (float*)d_out;

    int N = in_sizes[0] / IN_F;   // 50000
    int E = in_sizes[1];          // 800000
    int nb = (N + 255) / 256;     // 196 (<= 256 for scan3's internal scan)

    size_t off = 0;
    auto alloc = [&](size_t bytes) {
        size_t o = off;
        off = (off + bytes + 255) & ~(size_t)255;
        return o;
    };
    char* ws = (char*)d_ws;
    unsigned short* h16     = (unsigned short*)(ws + alloc((size_t)N * HD * 2));
    unsigned short* resid16 = (unsigned short*)(ws + alloc((size_t)N * HD * 2));
    __hip_bfloat16* w16     = (__hip_bfloat16*)(ws + alloc((size_t)2 * HD * IN_F * 2));
    unsigned short* ew16    = (unsigned short*)(ws + alloc((size_t)16 * IN_F * 2));
    float* el               = (float*)(ws + alloc((size_t)N * 4 * 4));
    float* er               = (float*)(ws + alloc((size_t)N * 4 * 4));
    int* out_cnt            = (int*)(ws + alloc((size_t)N * 4));
    int* deg                = (int*)(ws + alloc((size_t)N * 4));
    int* row_start          = (int*)(ws + alloc((size_t)(N + 1) * 4));
    int* bsum               = (int*)(ws + alloc((size_t)nb * 4));
    int* esrc               = (int*)(ws + alloc((size_t)E * 4));
    unsigned short* pc_src  = (unsigned short*)(ws + alloc((size_t)CSRC * N * 2));

    // runtime-adaptive dst-chunk count (each chunk = one uint16 row of N)
    size_t per_chunk = (size_t)2 * N;
    size_t avail = (ws_size > off + 4096) ? (ws_size - off - 4096) : 0;
    int C = (int)(avail / per_chunk);
    if (C > 128) C = 128;
    if (C < 32) C = 32;
    unsigned short* pc_dst = (unsigned short*)(ws + alloc((size_t)C * N * 2));
    int chunk = (E + C - 1) / C;
    int chunk_s = (E + CSRC - 1) / CSRC;

    int n4each = HD * IN_F / 4;
    int cvtb = (2 * n4each + 1023) / 1024;     // 16

    hist_cvt_kernel<<<C + CSRC + 1 + cvtb, 1024, 0, stream>>>(
        src, dst, pc_src, pc_dst,
        (const float4*)W_fc, (const float4*)W_res, W_fc, attn_l, attn_r,
        (ushort4*)w16, ew16, n4each, N, E, C, chunk, chunk_s);

    sum_scan1_kernel<<<nb, 256, 0, stream>>>(pc_src, pc_dst, out_cnt, deg, bsum, N, C);
    scan3_kernel<<<nb, 256, 0, stream>>>(deg, bsum, row_start, N, nb, E);

    int ntiles = (N + 31) / 32;
    place_gemm_kernel<<<C + GGRID, 1024, 0, stream>>>(
        src, dst, pc_dst, row_start, esrc,
        feat, (const __hip_bfloat16*)w16, (const __hip_bfloat16*)ew16, out_cnt,
        h16, resid16, el, er, N, E, C, chunk, ntiles);

    int nb4 = (N + 3) / 4;
    agg_kernel<<<nb4, 256, 0, stream>>>(h16, el, er, row_start, esrc, resid16, out, N);
}

// Round 18
// 127.437 us; speedup vs baseline: 1.1667x; 1.0450x over previous
//
#include <hip/hip_runtime.h>
#include <hip/hip_bf16.h>
#include <math.h>

#define HD 128          // N_HEADS * OUT_FEATS
#define IN_F 256
#define NEG_SLOPE 0.2f
#define NMAX 50000      // problem-fixed node count (LDS histogram capacity)
#define GGRID 256       // uniform place+gemm grid (1 block/CU)
#define CSRC 32         // src-histogram chunk count (only totals needed)

typedef __attribute__((ext_vector_type(8))) short short8;
typedef __attribute__((ext_vector_type(4))) float f32x4;

__device__ __forceinline__ unsigned short f2bf(float x) {
    __hip_bfloat16 b = __float2bfloat16(x);
    return *(unsigned short*)&b;
}
__device__ __forceinline__ float bf2f(unsigned short u) {
    unsigned int v = ((unsigned int)u) << 16;
    float f;
    __builtin_memcpy(&f, &v, 4);
    return f;
}
__device__ __forceinline__ short8 pack8(float4 f0, float4 f1) {
    short8 v;
    v[0] = (short)f2bf(f0.x); v[1] = (short)f2bf(f0.y);
    v[2] = (short)f2bf(f0.z); v[3] = (short)f2bf(f0.w);
    v[4] = (short)f2bf(f1.x); v[5] = (short)f2bf(f1.y);
    v[6] = (short)f2bf(f1.z); v[7] = (short)f2bf(f1.w);
    return v;
}

// ======== K1: histograms + weight conversion + ew columns, one launch ========
__global__ __launch_bounds__(1024) void hist_cvt_kernel(
    const int* __restrict__ src, const int* __restrict__ dst,
    unsigned short* __restrict__ pc_src, unsigned short* __restrict__ pc_dst,
    const float4* __restrict__ wfc4, const float4* __restrict__ wres4,
    const float* __restrict__ wfc, const float* __restrict__ attn_l,
    const float* __restrict__ attn_r, ushort4* __restrict__ w16,
    unsigned short* __restrict__ ew16, int n4each,
    int N, int E, int C, int chunk, int chunk_s) {
    __shared__ unsigned int h[NMAX / 2];   // 100 KB packed uint16 counts
    int tid = threadIdx.x;
    int b = blockIdx.x;

    if (b >= C + CSRC) {
        int rb = b - C - CSRC;
        if (rb == 0) {
            int hh = tid >> 8, k = tid & 255;
            float sl = 0.f, sr = 0.f;
#pragma unroll 8
            for (int d = 0; d < 32; d++) {
                float w = wfc[(size_t)(hh * 32 + d) * IN_F + k];
                sl += attn_l[hh * 32 + d] * w;
                sr += attn_r[hh * 32 + d] * w;
            }
            ew16[hh * IN_F + k] = f2bf(sl);
            ew16[(4 + hh) * IN_F + k] = f2bf(sr);
            ew16[(8 + hh) * IN_F + k] = 0;
            ew16[(12 + hh) * IN_F + k] = 0;
        } else {
            int idx = (rb - 1) * 1024 + tid;
            if (idx < 2 * n4each) {
                float4 f = (idx < n4each) ? wfc4[idx] : wres4[idx - n4each];
                ushort4 u;
                u.x = f2bf(f.x); u.y = f2bf(f.y); u.z = f2bf(f.z); u.w = f2bf(f.w);
                w16[idx] = u;
            }
        }
        return;
    }

    int nh = N >> 1;                        // N even
    uint4* h4 = (uint4*)h;
    for (int i = tid; i < (nh >> 2); i += 1024) h4[i] = make_uint4(0, 0, 0, 0);
    for (int i = (nh & ~3) + tid; i < nh; i += 1024) h[i] = 0;
    __syncthreads();

    bool isSrc = (b >= C);
    const int* arr = isSrc ? src : dst;
    int c = isSrc ? (b - C) : b;
    int ch = isSrc ? chunk_s : chunk;
    int e0 = c * ch, e1 = min(E, (c + 1) * ch);
    for (int e = e0 + tid; e < e1; e += 1024) {
        int v = arr[e];
        atomicAdd(&h[v >> 1], 1u << ((v & 1) << 4));
    }
    __syncthreads();

    unsigned short* pc = (isSrc ? pc_src : pc_dst) + (size_t)c * N;
    uint4* pc4 = (uint4*)pc;
    for (int i = tid; i < (nh >> 2); i += 1024) pc4[i] = h4[i];
    for (int i = (nh & ~3) + tid; i < nh; i += 1024) ((unsigned int*)pc)[i] = h[i];
}

// ---------------- per-node chunk prefix (in place) + degrees + scan1 ----------------
__global__ __launch_bounds__(256) void sum_scan1_kernel(
    const unsigned short* __restrict__ pc_src, unsigned short* __restrict__ pc_dst,
    int* __restrict__ out_cnt, int* __restrict__ deg, int* __restrict__ bsum,
    int N, int C) {
    __shared__ int wsum[4];
    int n = blockIdx.x * 256 + threadIdx.x;
    int sd = 0;
    if (n < N) {
        int ss = 0;
#pragma unroll 4
        for (int c = 0; c < CSRC; c++) ss += pc_src[(size_t)c * N + n];
        for (int c = 0; c < C; c++) {
            unsigned short v = pc_dst[(size_t)c * N + n];
            pc_dst[(size_t)c * N + n] = (unsigned short)sd;  // exclusive chunk prefix
            sd += v;
        }
        out_cnt[n] = ss;
        deg[n] = sd;
    }
    int v = (n < N) ? sd : 0;
#pragma unroll
    for (int d = 1; d < 64; d <<= 1) v += __shfl_xor(v, d);
    if ((threadIdx.x & 63) == 0) wsum[threadIdx.x >> 6] = v;
    __syncthreads();
    if (threadIdx.x == 0) bsum[blockIdx.x] = wsum[0] + wsum[1] + wsum[2] + wsum[3];
}

// ---------------- scan3 with internal block-sum scan; also zeroes tilectr ----------
__global__ __launch_bounds__(256) void scan3_kernel(const int* __restrict__ deg,
                                                    const int* __restrict__ bsum,
                                                    int* __restrict__ row_start,
                                                    int* __restrict__ tilectr,
                                                    int N, int nb, int E) {
    __shared__ int wsum[4];
    __shared__ int sbo[256];
    int tid = threadIdx.x, lane = tid & 63, wid = tid >> 6;
    {
        int v = (tid < nb) ? bsum[tid] : 0;
        int incl = v;
#pragma unroll
        for (int d = 1; d < 64; d <<= 1) {
            int t = __shfl_up(incl, d);
            if (lane >= d) incl += t;
        }
        if (lane == 63) wsum[wid] = incl;
        __syncthreads();
        int woff = 0;
        for (int w = 0; w < wid; w++) woff += wsum[w];
        sbo[tid] = woff + incl - v;    // exclusive prefix of block sums
        __syncthreads();
    }
    int boff = sbo[blockIdx.x];
    if (blockIdx.x == 0 && tid == 0) {
        row_start[N] = E;
        *tilectr = 0;
    }
    __syncthreads();

    int i = blockIdx.x * 256 + tid;
    int v = (i < N) ? deg[i] : 0;
    int incl = v;
#pragma unroll
    for (int d = 1; d < 64; d <<= 1) {
        int t = __shfl_up(incl, d);
        if (lane >= d) incl += t;
    }
    if (lane == 63) wsum[wid] = incl;
    __syncthreads();
    int woff = 0;
    for (int w = 0; w < wid; w++) woff += wsum[w];
    int excl = boff + woff + incl - v;
    if (i < N) row_start[i] = excl;
}

// ======== K3: place (blocks < C) then GEMM with dynamic tile stealing ========
// Uniform grid of GGRID blocks, 1 block/CU. Blocks bid<C first run place
// (LDS cursor table), then ALL blocks stage sB and pull 32-row GEMM tiles
// from a global atomic counter — late joiners steal fewer tiles, so the
// place phase fully overlaps the GEMM instead of staggering it.
__global__ __launch_bounds__(1024, 1) void place_gemm_kernel(
    const int* __restrict__ src, const int* __restrict__ dst,
    const unsigned short* __restrict__ chunkpre, const int* __restrict__ row_start,
    int* __restrict__ esrc,
    const float* __restrict__ feat, const __hip_bfloat16* __restrict__ w16,
    const __hip_bfloat16* __restrict__ ew16, const int* __restrict__ out_cnt,
    unsigned short* __restrict__ h16, unsigned short* __restrict__ resid16,
    float* __restrict__ el, float* __restrict__ er, int* __restrict__ tilectr,
    int N, int E, int C, int chunk, int ntiles) {
    __shared__ __align__(16) char smem[147520];   // 144 KiB union + steal slot
    int tid = threadIdx.x;

    if ((int)blockIdx.x < C) {
        // ---------------- place phase ----------------
        unsigned int* cur = (unsigned int*)smem;   // 100 KB packed uint16 cursors
        int nh = N >> 1;
        const unsigned short* cp = chunkpre + (size_t)blockIdx.x * N;
        const uint4* cp4 = (const uint4*)cp;
        uint4* cur4 = (uint4*)cur;
        for (int i = tid; i < (nh >> 2); i += 1024) cur4[i] = cp4[i];
        for (int i = (nh & ~3) + tid; i < nh; i += 1024)
            cur[i] = ((const unsigned int*)cp)[i];
        __syncthreads();

        int e1 = min(E, (int)(blockIdx.x + 1) * chunk);
        for (int e = blockIdx.x * chunk + tid; e < e1; e += 1024) {
            int d = dst[e], s = src[e];
            int sh = (d & 1) << 4;
            unsigned int old = atomicAdd(&cur[d >> 1], 1u << sh);
            int rank = (old >> sh) & 0xffff;
            esrc[row_start[d] + rank] = s;
        }
        __syncthreads();   // cursor table dead; smem reusable as sB
    }

    // ---------------- gemm phase (all blocks) ----------------
    unsigned short* sB = (unsigned short*)smem;              // 128 KiB
    unsigned short* sA = (unsigned short*)(smem + 131072);   // 16 KiB
    int* sT = (int*)(smem + 147456);
    int lane = tid & 63, w = tid >> 6;        // 16 waves
    int l15 = lane & 15, lg = lane >> 4;
    int c0 = w * 16;
    bool w0 = (w == 0);
    bool isH = (w < 8);
    int colloc = c0 & 127;

    // stage B once: 8192 granules (8 per thread), XOR-swizzled by col
#pragma unroll
    for (int it = 0; it < 8; ++it) {
        int idx = it * 1024 + tid;
        int c = idx >> 5, g = idx & 31;
        short8 v = *(const short8*)(w16 + (size_t)c * IN_F + g * 8);
        *(short8*)&sB[c * 256 + ((g ^ (c & 7)) * 8)] = v;
    }
    short8 ereg[8];
    if (w0) {
        const __hip_bfloat16* ep = ew16 + (size_t)l15 * IN_F + lg * 8;
#pragma unroll
        for (int kk = 0; kk < 8; kk++) ereg[kk] = *(const short8*)(ep + kk * 32);
    }

    int srow = tid >> 5, sgc = tid & 31;      // one A granule per thread

    // steal first tile
    if (tid == 0) *sT = atomicAdd(tilectr, 1);
    __syncthreads();                          // sB staged + sT visible
    int t = *sT;
    float4 fA0, fA1;
    if (t < ntiles) {
        int gm = t * 32 + srow;
        gm = (gm < N) ? gm : (N - 1);
        const float4* fp = (const float4*)(feat + (size_t)gm * IN_F + sgc * 8);
        fA0 = fp[0];
        fA1 = fp[1];
    }

    while (t < ntiles) {
        __syncthreads();   // prior sA reads complete (no-op first iteration)
        *(short8*)&sA[srow * 256 + ((sgc ^ (srow & 7)) * 8)] = pack8(fA0, fA1);
        if (tid == 0) *sT = atomicAdd(tilectr, 1);   // steal next (latency hides)
        __syncthreads();   // sA staged + sT visible

        int tn = *sT;
        if (tn < ntiles) {
            int gm = tn * 32 + srow;
            gm = (gm < N) ? gm : (N - 1);
            const float4* fp = (const float4*)(feat + (size_t)gm * IN_F + sgc * 8);
            fA0 = fp[0];
            fA1 = fp[1];
        }

        f32x4 acc[2], accE[2];
#pragma unroll
        for (int i = 0; i < 2; i++) {
            acc[i] = (f32x4){0.f, 0.f, 0.f, 0.f};
            accE[i] = (f32x4){0.f, 0.f, 0.f, 0.f};
        }
#pragma unroll
        for (int kk = 0; kk < 8; kk++) {
            short8 a[2], b;
#pragma unroll
            for (int mi = 0; mi < 2; mi++) {
                int row = mi * 16 + l15;
                int gs = (kk * 4 + lg) ^ (row & 7);
                a[mi] = *(const short8*)&sA[row * 256 + gs * 8];
            }
            {
                int c = c0 + l15;
                int gsb = (kk * 4 + lg) ^ (c & 7);
                b = *(const short8*)&sB[c * 256 + gsb * 8];
            }
#pragma unroll
            for (int mi = 0; mi < 2; mi++)
                acc[mi] = __builtin_amdgcn_mfma_f32_16x16x32_bf16(a[mi], b, acc[mi],
                                                                  0, 0, 0);
            if (w0) {
#pragma unroll
                for (int mi = 0; mi < 2; mi++)
                    accE[mi] = __builtin_amdgcn_mfma_f32_16x16x32_bf16(
                        a[mi], ereg[kk], accE[mi], 0, 0, 0);
            }
        }

        int bm = t * 32;
#pragma unroll
        for (int mi = 0; mi < 2; mi++) {
#pragma unroll
            for (int reg = 0; reg < 4; reg++) {
                int r = bm + mi * 16 + lg * 4 + reg;
                bool valid = (r < N);
                int rr = valid ? r : 0;
                if (isH) {
                    float nrm = rsqrtf(fmaxf((float)out_cnt[rr], 1.0f));
                    if (valid) {
                        h16[(size_t)r * HD + colloc + l15] = f2bf(acc[mi][reg] * nrm);
                        if (w0) {
                            float ev = accE[mi][reg];  // l15<4: el, 4..7: er
                            if (l15 < 4) el[r * 4 + l15] = ev * nrm;
                            else if (l15 < 8) er[r * 4 + (l15 - 4)] = ev;
                        }
                    }
                } else if (valid) {
                    resid16[(size_t)r * HD + colloc + l15] = f2bf(acc[mi][reg]);
                }
            }
        }
        t = tn;
    }
}

// ---------------- fused edge softmax + weighted scatter + final ----------------
// One wave per dst node, lane-transposed: 64 lanes = 4 edge-slots x 16 dim-lanes.
// 8-edge chunks, 2-stage software pipeline. Final write = sc*acc + resid16.
__global__ __launch_bounds__(256) void agg_kernel(const unsigned short* __restrict__ h16,
                                                  const float* __restrict__ el,
                                                  const float* __restrict__ er,
                                                  const int* __restrict__ row_start,
                                                  const int* __restrict__ esrc,
                                                  const unsigned short* __restrict__ resid16,
                                                  float* __restrict__ out, int N) {
    int wid = threadIdx.x >> 6, lane = threadIdx.x & 63;
    int n = blockIdx.x * 4 + wid;
    if (n >= N) return;
    int es = lane >> 4;        // edge slot 0..3
    int l15 = lane & 15;
    int h = l15 >> 2;          // head owning this lane's 8 dims
    int d0 = l15 * 8;
    int beg = row_start[n], end = row_start[n + 1];
    float erh = er[n * 4 + h];
    float den = 0.f;
    float acc[8];
#pragma unroll
    for (int j = 0; j < 8; j++) acc[j] = 0.f;

    if (beg < end) {
        bool ok0, ok1;
        float ev0, ev1; short8 hv0, hv1;
        {
            int i0 = beg + es, i1 = beg + 4 + es;
            ok0 = i0 < end; ok1 = i1 < end;
            int s0 = esrc[ok0 ? i0 : beg];
            int s1 = esrc[ok1 ? i1 : beg];
            ev0 = el[s0 * 4 + h]; ev1 = el[s1 * 4 + h];
            hv0 = *(const short8*)(h16 + (size_t)s0 * HD + d0);
            hv1 = *(const short8*)(h16 + (size_t)s1 * HD + d0);
        }
        for (int base = beg + 8; base < end; base += 8) {
            int i0 = base + es, i1 = base + 4 + es;
            bool p0 = i0 < end, p1 = i1 < end;
            int t0 = esrc[p0 ? i0 : beg];
            int t1 = esrc[p1 ? i1 : beg];
            float fv0 = el[t0 * 4 + h];
            float fv1 = el[t1 * 4 + h];
            short8 g0 = *(const short8*)(h16 + (size_t)t0 * HD + d0);
            short8 g1 = *(const short8*)(h16 + (size_t)t1 * HD + d0);
            float e0 = ev0 + erh; e0 = (e0 > 0.f) ? e0 : NEG_SLOPE * e0;
            float e1 = ev1 + erh; e1 = (e1 > 0.f) ? e1 : NEG_SLOPE * e1;
            float ex0 = ok0 ? __expf(e0) : 0.f;
            float ex1 = ok1 ? __expf(e1) : 0.f;
            den += ex0 + ex1;
#pragma unroll
            for (int j = 0; j < 8; j++)
                acc[j] += ex0 * bf2f((unsigned short)hv0[j]) +
                          ex1 * bf2f((unsigned short)hv1[j]);
            ok0 = p0; ok1 = p1; ev0 = fv0; ev1 = fv1; hv0 = g0; hv1 = g1;
        }
        float e0 = ev0 + erh; e0 = (e0 > 0.f) ? e0 : NEG_SLOPE * e0;
        float e1 = ev1 + erh; e1 = (e1 > 0.f) ? e1 : NEG_SLOPE * e1;
        float ex0 = ok0 ? __expf(e0) : 0.f;
        float ex1 = ok1 ? __expf(e1) : 0.f;
        den += ex0 + ex1;
#pragma unroll
        for (int j = 0; j < 8; j++)
            acc[j] += ex0 * bf2f((unsigned short)hv0[j]) +
                      ex1 * bf2f((unsigned short)hv1[j]);
    }

    // reduce over the 4 edge slots (lanes differing in bits 4,5)
#pragma unroll
    for (int m = 16; m < 64; m <<= 1) {
        den += __shfl_xor(den, m);
#pragma unroll
        for (int j = 0; j < 8; j++) acc[j] += __shfl_xor(acc[j], m);
    }

    if (es == 0) {
        const unsigned short* rp = resid16 + (size_t)n * HD + d0;
        short8 rv = *(const short8*)rp;
        int indeg = end - beg;
        float sc = (indeg > 0) ? sqrtf((float)indeg) / den : 0.f;
        float o[8];
#pragma unroll
        for (int j = 0; j < 8; j++)
            o[j] = sc * acc[j] + bf2f((unsigned short)rv[j]);
        float* op = out + (size_t)n * HD + d0;
        *(float4*)op = make_float4(o[0], o[1], o[2], o[3]);
        *(float4*)(op + 4) = make_float4(o[4], o[5], o[6], o[7]);
    }
}

extern "C" void kernel_launch(void* const* d_in, const int* in_sizes, int n_in,
                              void* d_out, int out_size, void* d_ws, size_t ws_size,
                              hipStream_t stream) {
    const float* feat   = (const float*)d_in[0];
    const int*   src    = (const int*)d_in[1];
    const int*   dst    = (const int*)d_in[2];
    const float* W_fc   = (const float*)d_in[3];
    const float* attn_l = (const float*)d_in[4];
    const float* attn_r = (const float*)d_in[5];
    const float* W_res  = (const float*)d_in[6];
    float* out = (float*)d_out;

    int N = in_sizes[0] / IN_F;   // 50000
    int E = in_sizes[1];          // 800000
    int nb = (N + 255) / 256;     // 196 (<= 256 for scan3's internal scan)

    size_t off = 0;
    auto alloc = [&](size_t bytes) {
        size_t o = off;
        off = (off + bytes + 255) & ~(size_t)255;
        return o;
    };
    char* ws = (char*)d_ws;
    unsigned short* h16     = (unsigned short*)(ws + alloc((size_t)N * HD * 2));
    unsigned short* resid16 = (unsigned short*)(ws + alloc((size_t)N * HD * 2));
    __hip_bfloat16* w16     = (__hip_bfloat16*)(ws + alloc((size_t)2 * HD * IN_F * 2));
    unsigned short* ew16    = (unsigned short*)(ws + alloc((size_t)16 * IN_F * 2));
    float* el               = (float*)(ws + alloc((size_t)N * 4 * 4));
    float* er               = (float*)(ws + alloc((size_t)N * 4 * 4));
    int* out_cnt            = (int*)(ws + alloc((size_t)N * 4));
    int* deg                = (int*)(ws + alloc((size_t)N * 4));
    int* row_start          = (int*)(ws + alloc((size_t)(N + 1) * 4));
    int* bsum               = (int*)(ws + alloc((size_t)nb * 4));
    int* tilectr            = (int*)(ws + alloc(256));
    int* esrc               = (int*)(ws + alloc((size_t)E * 4));
    unsigned short* pc_src  = (unsigned short*)(ws + alloc((size_t)CSRC * N * 2));

    // runtime-adaptive dst-chunk count (each chunk = one uint16 row of N)
    size_t per_chunk = (size_t)2 * N;
    size_t avail = (ws_size > off + 4096) ? (ws_size - off - 4096) : 0;
    int C = (int)(avail / per_chunk);
    if (C > 128) C = 128;         // must stay <= GGRID
    if (C < 32) C = 32;
    unsigned short* pc_dst = (unsigned short*)(ws + alloc((size_t)C * N * 2));
    int chunk = (E + C - 1) / C;
    int chunk_s = (E + CSRC - 1) / CSRC;

    int n4each = HD * IN_F / 4;
    int cvtb = (2 * n4each + 1023) / 1024;     // 16

    hist_cvt_kernel<<<C + CSRC + 1 + cvtb, 1024, 0, stream>>>(
        src, dst, pc_src, pc_dst,
        (const float4*)W_fc, (const float4*)W_res, W_fc, attn_l, attn_r,
        (ushort4*)w16, ew16, n4each, N, E, C, chunk, chunk_s);

    sum_scan1_kernel<<<nb, 256, 0, stream>>>(pc_src, pc_dst, out_cnt, deg, bsum, N, C);
    scan3_kernel<<<nb, 256, 0, stream>>>(deg, bsum, row_start, tilectr, N, nb, E);

    int ntiles = (N + 31) / 32;
    place_gemm_kernel<<<GGRID, 1024, 0, stream>>>(
        src, dst, pc_dst, row_start, esrc,
        feat, (const __hip_bfloat16*)w16, (const __hip_bfloat16*)ew16, out_cnt,
        h16, resid16, el, er, tilectr, N, E, C, chunk, ntiles);

    int nb4 = (N + 3) / 4;
    agg_kernel<<<nb4, 256, 0, stream>>>(h16, el, er, row_start, esrc, resid16, out, N);
}